// Round 4
// baseline (13140.689 us; speedup 1.0000x reference)
//
#include <hip/hip_runtime.h>
#include <cstdint>
#include <cstddef>
#include <string.h>

typedef __bf16 bf16;
typedef bf16 bf16x4 __attribute__((ext_vector_type(4)));
typedef bf16 bf16x8 __attribute__((ext_vector_type(8)));
typedef float f32x4 __attribute__((ext_vector_type(4)));
typedef unsigned long long u64;

#define B_   64
#define T_   512
#define I_   1024
#define H_   1024
#define BT_  32768
#define NBL  64    // lstm blocks
#define NJ   16    // hidden units per lstm block

// ---- ws layout (bytes) ----
#define WS_XBF   ((size_t)0)              // x as bf16 [32768][1024]            : 67108864
#define WS_WXP   ((size_t)67108864)       // Wx^T bf16 [4096][1024]             : 8388608
#define WS_WHP   ((size_t)75497472)       // Wh packed bf16 [64][128][64][8]    : 8388608
#define WS_XG    ((size_t)83886080)       // xg bf16 [512][64][64][64]          : 268435456
#define WS_HB    ((size_t)352321536)      // h bf16 [chain2][par2][32][1024]    : 262144
#define WS_ARR   ((size_t)352583680)      // flags u32[2][64] @128B stride      : 16384
#define WS_NEED  ((size_t)352600064)

#define GLD_LDS16(gptr, lptr) \
  __builtin_amdgcn_global_load_lds((const __attribute__((address_space(1))) void*)(gptr), \
                                   (__attribute__((address_space(3))) void*)(lptr), 16, 0, 0)

__device__ __forceinline__ float sigmoidf_(float x) { return 1.0f / (1.0f + __expf(-x)); }
// branch-free tanh: 1 - 2/(e^{2x}+1); saturates correctly for |x| large (no NaN).
__device__ __forceinline__ float tanhf_(float x) { float e = __expf(2.0f * x); return 1.0f - 2.0f / (e + 1.0f); }
__device__ __forceinline__ float lo2f(unsigned u) { unsigned v = u << 16; float f; memcpy(&f, &v, 4); return f; }
__device__ __forceinline__ float hi2f(unsigned u) { unsigned v = u & 0xffff0000u; float f; memcpy(&f, &v, 4); return f; }
__device__ __forceinline__ unsigned short b2s(bf16 h) { unsigned short s; memcpy(&s, &h, 2); return s; }

// ---------------- pack kernels ----------------

__global__ __launch_bounds__(256) void k_cvt_x(const float4* __restrict__ in,
                                               bf16* __restrict__ out, int n4) {
  int i = blockIdx.x * blockDim.x + threadIdx.x;
  int stride = gridDim.x * blockDim.x;
  for (; i < n4; i += stride) {
    float4 v = in[i];
    bf16x4 r = { (bf16)v.x, (bf16)v.y, (bf16)v.z, (bf16)v.w };
    *(bf16x4*)(out + (size_t)i * 4) = r;
  }
}

// Wx^T: wxp[(gate*1024 + n)][k] = W[k][n]   (32x32 LDS tile transpose)
__global__ __launch_bounds__(256) void k_pack_wx(const float* __restrict__ W,
                                                 bf16* __restrict__ wxp, int gate) {
  __shared__ bf16 tile[32][33];
  int bx = blockIdx.x & 31, by = blockIdx.x >> 5;
  int tx = threadIdx.x & 31, ty = threadIdx.x >> 5;
  int k0 = by * 32, n0 = bx * 32;
  for (int r = 0; r < 32; r += 8)
    tile[ty + r][tx] = (bf16)W[(size_t)(k0 + ty + r) * H_ + n0 + tx];
  __syncthreads();
  for (int r = 0; r < 32; r += 8)
    wxp[(size_t)(gate * H_ + n0 + ty + r) * I_ + k0 + tx] = tile[tx][ty + r];
}

// Wh packed: whp[blk][k>>3][gate*16 + (u&15)][k&7] = W[k][u],  blk = u>>4
__global__ __launch_bounds__(256) void k_pack_wh(const float* __restrict__ W,
                                                 bf16* __restrict__ whp, int gate) {
  __shared__ bf16 tile[32][33];
  int bx = blockIdx.x & 31, by = blockIdx.x >> 5;
  int tx = threadIdx.x & 31, ty = threadIdx.x >> 5;
  int k0 = by * 32, u0 = bx * 32;
  for (int r = 0; r < 32; r += 8)
    tile[ty + r][tx] = (bf16)W[(size_t)(k0 + ty + r) * H_ + u0 + tx];
  __syncthreads();
  for (int r = 0; r < 32; r += 8) {
    int u = u0 + ty + r;
    int k = k0 + tx;
    size_t addr = ((size_t)(u >> 4) * 128 + (k >> 3)) * 512 +
                  (size_t)(gate * 16 + (u & 15)) * 8 + (k & 7);
    whp[addr] = tile[tx][ty + r];
  }
}

// ---------------- phase 1: xg = x @ Wx  (bf16 MFMA, m97-style) ----------------
__global__ __launch_bounds__(256) void k_gemm_xg(const bf16* __restrict__ A,
                                                 const bf16* __restrict__ Bt,
                                                 bf16* __restrict__ xg) {
  __shared__ bf16 As[128 * 64];
  __shared__ bf16 Bs[128 * 64];
  int bid = blockIdx.x;
  int bm = bid >> 5, bn = bid & 31;
  int m0 = bm * 128, n0 = bn * 128;
  int tid = threadIdx.x, lane = tid & 63, w = tid >> 6;
  int lr = lane & 15, lk = lane >> 4;
  int sr = lane >> 3, sk = (lane & 7) * 8;
  int wm = (w >> 1) * 64, wn = (w & 1) * 64;
  f32x4 acc[4][4] = {};

  for (int k0 = 0; k0 < 1024; k0 += 64) {
    __syncthreads();
    for (int i = 0; i < 4; ++i) {
      int idx = w * 4 + i;
      const bf16* ga = A + (size_t)(m0 + idx * 8 + sr) * 1024 + k0 + sk;
      GLD_LDS16(ga, &As[idx * 512]);
      const bf16* gb = Bt + (size_t)(n0 + idx * 8 + sr) * 1024 + k0 + sk;
      GLD_LDS16(gb, &Bs[idx * 512]);
    }
    asm volatile("s_waitcnt vmcnt(0)" ::: "memory");
    __syncthreads();
#pragma unroll
    for (int kk = 0; kk < 64; kk += 32) {
      bf16x8 af[4], bfr[4];
#pragma unroll
      for (int i = 0; i < 4; ++i)
        af[i] = *(const bf16x8*)&As[(wm + i * 16 + lr) * 64 + kk + lk * 8];
#pragma unroll
      for (int j = 0; j < 4; ++j)
        bfr[j] = *(const bf16x8*)&Bs[(wn + j * 16 + lr) * 64 + kk + lk * 8];
#pragma unroll
      for (int i = 0; i < 4; ++i)
#pragma unroll
        for (int j = 0; j < 4; ++j)
          acc[i][j] = __builtin_amdgcn_mfma_f32_16x16x32_bf16(af[i], bfr[j], acc[i][j], 0, 0, 0);
    }
  }
  // epilogue: scatter into xg[t][blk][b][c],  blk = u>>4, c = gate*16 + (u&15)
#pragma unroll
  for (int i = 0; i < 4; ++i) {
#pragma unroll
    for (int j = 0; j < 4; ++j) {
      int n = n0 + wn + j * 16 + lr;
      int u = n & 1023, g = n >> 10;
      int blk = u >> 4, c = g * 16 + (u & 15);
      int mb = m0 + wm + i * 16 + lk * 4;
#pragma unroll
      for (int r = 0; r < 4; ++r) {
        int m = mb + r;
        int t = m & 511, bb = m >> 9;
        xg[(((size_t)t * NBL + blk) * B_ + bb) * 64 + c] = (bf16)acc[i][j][r];
      }
    }
  }
}

// ---------------- phase 2: persistent LSTM scan, 2 interleaved batch-chains ----------------
// 64 blocks x 512 threads. Block owns 16 units. Chain 0 = rows 0..31, chain 1 = rows 32..63.
// Per tick: [poll A][GEMM+gates A][publish+flag A][poll B][GEMM+gates B][publish+flag B].
// Chain B's RT hides under chain A's compute and vice versa.
// Wave mapping per segment: w -> (kh = w>>2 [K half], nq = w&3 [16-col group]);
// each wave does BOTH 16-row groups -> B-fragments partition exactly (no redundancy).
#define SEG(CH, XV, CC0, CC1)                                                              \
  do {                                                                                     \
    if (t > 0) {                                                                           \
      if (w == 0) {                                                                        \
        unsigned v_;                                                                       \
        do {                                                                               \
          v_ = __hip_atomic_load(arr + ((CH) * 64 + lane) * 32, __ATOMIC_RELAXED,          \
                                 __HIP_MEMORY_SCOPE_AGENT);                                \
        } while (!__all((int)(v_ >= (unsigned)t)));                                        \
      }                                                                                    \
      __syncthreads();                                                                     \
      __builtin_amdgcn_fence(__ATOMIC_ACQUIRE, "agent");                                   \
      __builtin_amdgcn_sched_barrier(0);                                                   \
    }                                                                                      \
    {                                                                                      \
      const bf16* hsrc = hb + (((CH) * 2 + (t & 1)) * 32768);                              \
      const bf16* hr0 = hsrc + lr * 1024 + kh * 512 + lk * 8;                              \
      f32x4 acc0 = {}, acc1 = {};                                                          \
      _Pragma("unroll")                                                                    \
      for (int i = 0; i < 16; ++i) {                                                       \
        bf16x8 a0 = *(const bf16x8*)(hr0 + i * 32);                                        \
        bf16x8 a1 = *(const bf16x8*)(hr0 + 16384 + i * 32);                                \
        bf16x8 bbf = *(const bf16x8*)&whl[((kh * 64 + i * 4 + lk) * 64 + nq * 16 + lr) * 8]; \
        acc0 = __builtin_amdgcn_mfma_f32_16x16x32_bf16(a0, bbf, acc0, 0, 0, 0);            \
        acc1 = __builtin_amdgcn_mfma_f32_16x16x32_bf16(a1, bbf, acc1, 0, 0, 0);            \
      }                                                                                    \
      int gr = kh * 2048 + lk * 256 + nq * 16 + lr;                                        \
      _Pragma("unroll")                                                                    \
      for (int r = 0; r < 4; ++r) {                                                        \
        gl[gr + r * 64] = acc0[r];                                                         \
        gl[gr + 1024 + r * 64] = acc1[r];                                                  \
      }                                                                                    \
    }                                                                                      \
    __syncthreads();                                                                       \
    if (tid < 256) {                                                                       \
      int gb = (CH) * 32 + bidx;                                                           \
      float s0, s1, s2, s3, s4, s5, s6, s7;                                                \
      {                                                                                    \
        int c0 = bidx * 64 + eu2 * 2;                                                      \
        s0 = gl[c0] + gl[2048 + c0];           s1 = gl[c0 + 1] + gl[2048 + c0 + 1];        \
        s2 = gl[c0 + 16] + gl[2048 + c0 + 16]; s3 = gl[c0 + 17] + gl[2048 + c0 + 17];      \
        s4 = gl[c0 + 32] + gl[2048 + c0 + 32]; s5 = gl[c0 + 33] + gl[2048 + c0 + 33];      \
        s6 = gl[c0 + 48] + gl[2048 + c0 + 48]; s7 = gl[c0 + 49] + gl[2048 + c0 + 49];      \
      }                                                                                    \
      float gi0 = s0 + lo2f(XV[0]) + bi0, gi1 = s1 + hi2f(XV[0]) + bi1;                    \
      float gf0 = s2 + lo2f(XV[1]) + bf0, gf1 = s3 + hi2f(XV[1]) + bf1;                    \
      float gg0 = s4 + lo2f(XV[2]) + bg0, gg1 = s5 + hi2f(XV[2]) + bg1;                    \
      float go0 = s6 + lo2f(XV[3]) + bo0, go1 = s7 + hi2f(XV[3]) + bo1;                    \
      CC0 = sigmoidf_(gf0) * CC0 + sigmoidf_(gi0) * tanhf_(gg0);                           \
      CC1 = sigmoidf_(gf1) * CC1 + sigmoidf_(gi1) * tanhf_(gg1);                           \
      float hv0 = sigmoidf_(go0) * tanhf_(CC0);                                            \
      float hv1 = sigmoidf_(go1) * tanhf_(CC1);                                            \
      if (t == T_ - 1) {                                                                   \
        out[(size_t)gb * H_ + u0g] = hv0;                                                  \
        out[(size_t)gb * H_ + u1g] = hv1;                                                  \
        out[(size_t)B_ * H_ + gb * H_ + u0g] = CC0;                                        \
        out[(size_t)B_ * H_ + gb * H_ + u1g] = CC1;                                        \
      } else {                                                                             \
        unsigned hp = (unsigned)b2s((bf16)hv0) | ((unsigned)b2s((bf16)hv1) << 16);         \
        *(unsigned*)(hb + ((CH) * 2 + ((t + 1) & 1)) * 32768 + bidx * 1024 + blk * 16 +    \
                     eu2 * 2) = hp;                                                        \
      }                                                                                    \
    }                                                                                      \
    __syncthreads();                                                                       \
    if (t < T_ - 1) {                                                                      \
      if (tid == 0) {                                                                      \
        __builtin_amdgcn_fence(__ATOMIC_RELEASE, "agent");                                 \
        __hip_atomic_store(arr + ((CH) * 64 + blk) * 32, (unsigned)(t + 1),                \
                           __ATOMIC_RELAXED, __HIP_MEMORY_SCOPE_AGENT);                    \
      }                                                                                    \
      if (tid < 256) {                                                                     \
        size_t xb = (((size_t)(t + 1) * NBL + blk) * B_ + (CH) * 32 + bidx) * 32;          \
        _Pragma("unroll")                                                                  \
        for (int g = 0; g < 4; ++g) XV[g] = xgw[xb + g * 8 + eu2];                         \
      }                                                                                    \
    }                                                                                      \
  } while (0)

__global__ __launch_bounds__(512) void k_lstm(const bf16* __restrict__ xg,
                                              const bf16* __restrict__ whp,
                                              bf16* hb,              // [2][2][32][1024]
                                              float* __restrict__ out,
                                              unsigned* arr,         // [2][64] @ 32-u32 stride
                                              const float* __restrict__ bii, const float* __restrict__ bhi,
                                              const float* __restrict__ bif, const float* __restrict__ bhf,
                                              const float* __restrict__ big, const float* __restrict__ bhg,
                                              const float* __restrict__ bio, const float* __restrict__ bho) {
  __shared__ bf16 whl[65536];          // 128 KB: [kg][c][8]
  __shared__ float gl[2 * 32 * 64];    // 16 KB:  [kh][row][col]
  int blk = blockIdx.x;
  int tid = threadIdx.x;
  int lane = tid & 63, w = tid >> 6;
  int lr = lane & 15, lk = lane >> 4;
  int kh = w >> 2, nq = w & 3;

  {  // stage Wh slice: 128KB contiguous
    const bf16* src = whp + (size_t)blk * 65536;
#pragma unroll
    for (int i = 0; i < 16; ++i)
      *(bf16x8*)&whl[(size_t)(i * 512 + tid) * 8] = *(const bf16x8*)&src[(size_t)(i * 512 + tid) * 8];
  }

  // gates mapping (tid<256): bidx = row within chain, eu2 -> unit pair
  int bidx = tid >> 3;                 // 0..31 for tid<256
  int eu2 = tid & 7;
  int u0g = blk * NJ + eu2 * 2, u1g = u0g + 1;
  float bi0 = bii[u0g] + bhi[u0g], bi1 = bii[u1g] + bhi[u1g];
  float bf0 = bif[u0g] + bhf[u0g], bf1 = bif[u1g] + bhf[u1g];
  float bg0 = big[u0g] + bhg[u0g], bg1 = big[u1g] + bhg[u1g];
  float bo0 = bio[u0g] + bho[u0g], bo1 = bio[u1g] + bho[u1g];
  float cA0 = 0.f, cA1 = 0.f, cB0 = 0.f, cB1 = 0.f;

  // xg preload t=0 for both chains
  const unsigned* xgw = (const unsigned*)xg;
  unsigned xvA[4], xvB[4];
  if (tid < 256) {
    size_t xa = (((size_t)0 * NBL + blk) * B_ + 0 * 32 + bidx) * 32;
    size_t xb = (((size_t)0 * NBL + blk) * B_ + 1 * 32 + bidx) * 32;
#pragma unroll
    for (int g = 0; g < 4; ++g) { xvA[g] = xgw[xa + g * 8 + eu2]; xvB[g] = xgw[xb + g * 8 + eu2]; }
  }
  __syncthreads();

  for (int t = 0; t < T_; ++t) {
    SEG(0, xvA, cA0, cA1);
    SEG(1, xvB, cB0, cB1);
  }
}

// ---------------- launcher ----------------

extern "C" void kernel_launch(void* const* d_in, const int* in_sizes, int n_in,
                              void* d_out, int out_size, void* d_ws, size_t ws_size,
                              hipStream_t stream) {
  if (ws_size < WS_NEED) return;

  const float* x = (const float*)d_in[0];
  const float* W_ii = (const float*)d_in[1];
  const float* W_hi = (const float*)d_in[2];
  const float* W_if = (const float*)d_in[3];
  const float* W_hf = (const float*)d_in[4];
  const float* W_ig = (const float*)d_in[5];
  const float* W_hg = (const float*)d_in[6];
  const float* W_io = (const float*)d_in[7];
  const float* W_ho = (const float*)d_in[8];
  const float* b_ii = (const float*)d_in[9];
  const float* b_hi = (const float*)d_in[10];
  const float* b_if = (const float*)d_in[11];
  const float* b_hf = (const float*)d_in[12];
  const float* b_ig = (const float*)d_in[13];
  const float* b_hg = (const float*)d_in[14];
  const float* b_io = (const float*)d_in[15];
  const float* b_ho = (const float*)d_in[16];

  char* ws = (char*)d_ws;
  bf16* xbf = (bf16*)(ws + WS_XBF);
  bf16* wxp = (bf16*)(ws + WS_WXP);
  bf16* whp = (bf16*)(ws + WS_WHP);
  bf16* xgp = (bf16*)(ws + WS_XG);
  bf16* hbp = (bf16*)(ws + WS_HB);
  unsigned* arrp = (unsigned*)(ws + WS_ARR);
  float* outp = (float*)d_out;

  // zero h0 buffers (both chains/parities) + arrival flags (contiguous)
  hipMemsetAsync(ws + WS_HB, 0, 262144 + 16384, stream);

  // pack
  k_cvt_x<<<2048, 256, 0, stream>>>((const float4*)x, xbf, BT_ * I_ / 4);
  const float* wx_g[4] = {W_ii, W_if, W_ig, W_io};
  const float* wh_g[4] = {W_hi, W_hf, W_hg, W_ho};
  for (int g = 0; g < 4; ++g) {
    k_pack_wx<<<1024, 256, 0, stream>>>(wx_g[g], wxp, g);
    k_pack_wh<<<1024, 256, 0, stream>>>(wh_g[g], whp, g);
  }

  // phase 1 GEMM
  k_gemm_xg<<<dim3(256 * 32), 256, 0, stream>>>(xbf, wxp, xgp);

  // phase 2 cooperative scan
  void* args[] = {
      (void*)&xgp, (void*)&whp, (void*)&hbp, (void*)&outp, (void*)&arrp,
      (void*)&b_ii, (void*)&b_hi, (void*)&b_if, (void*)&b_hf,
      (void*)&b_ig, (void*)&b_hg, (void*)&b_io, (void*)&b_ho};
  hipLaunchCooperativeKernel((const void*)k_lstm, dim3(NBL), dim3(512), args, 0, stream);
}

// Round 5
// 5519.587 us; speedup vs baseline: 2.3807x; 2.3807x over previous
//
#include <hip/hip_runtime.h>
#include <cstdint>
#include <cstddef>
#include <string.h>

typedef __bf16 bf16;
typedef bf16 bf16x4 __attribute__((ext_vector_type(4)));
typedef bf16 bf16x8 __attribute__((ext_vector_type(8)));
typedef float f32x4 __attribute__((ext_vector_type(4)));
typedef unsigned long long u64;

#define B_   64
#define T_   512
#define I_   1024
#define H_   1024
#define BT_  32768
#define NBL  64    // lstm blocks
#define NJ   16    // hidden units per lstm block

// ---- ws layout (bytes) ----
#define WS_XBF   ((size_t)0)              // x as bf16 [32768][1024]            : 67108864
#define WS_WXP   ((size_t)67108864)       // Wx^T bf16 [4096][1024]             : 8388608
#define WS_WHP   ((size_t)75497472)       // Wh packed bf16 [64][128][64][8]    : 8388608
#define WS_XG    ((size_t)83886080)       // xg bf16 [512][64][64][64]          : 268435456
#define WS_HB    ((size_t)352321536)      // h dbuf bf16 [2][64][1024]          : 262144
#define WS_ARR   ((size_t)352583680)      // flags u32[64] @128B stride         : 8192
#define WS_NEED  ((size_t)352600064)

#define GLD_LDS16(gptr, lptr) \
  __builtin_amdgcn_global_load_lds((const __attribute__((address_space(1))) void*)(gptr), \
                                   (__attribute__((address_space(3))) void*)(lptr), 16, 0, 0)

__device__ __forceinline__ float sigmoidf_(float x) { return 1.0f / (1.0f + __expf(-x)); }
// branch-free tanh: 1 - 2/(e^{2x}+1); saturates correctly for |x| large (no NaN).
__device__ __forceinline__ float tanhf_(float x) { float e = __expf(2.0f * x); return 1.0f - 2.0f / (e + 1.0f); }
__device__ __forceinline__ float lo2f(unsigned u) { unsigned v = u << 16; float f; memcpy(&f, &v, 4); return f; }
__device__ __forceinline__ float hi2f(unsigned u) { unsigned v = u & 0xffff0000u; float f; memcpy(&f, &v, 4); return f; }
__device__ __forceinline__ unsigned short b2s(bf16 h) { unsigned short s; memcpy(&s, &h, 2); return s; }

// ---------------- pack kernels ----------------

__global__ __launch_bounds__(256) void k_cvt_x(const float4* __restrict__ in,
                                               bf16* __restrict__ out, int n4) {
  int i = blockIdx.x * blockDim.x + threadIdx.x;
  int stride = gridDim.x * blockDim.x;
  for (; i < n4; i += stride) {
    float4 v = in[i];
    bf16x4 r = { (bf16)v.x, (bf16)v.y, (bf16)v.z, (bf16)v.w };
    *(bf16x4*)(out + (size_t)i * 4) = r;
  }
}

// Wx^T: wxp[(gate*1024 + n)][k] = W[k][n]   (32x32 LDS tile transpose)
__global__ __launch_bounds__(256) void k_pack_wx(const float* __restrict__ W,
                                                 bf16* __restrict__ wxp, int gate) {
  __shared__ bf16 tile[32][33];
  int bx = blockIdx.x & 31, by = blockIdx.x >> 5;
  int tx = threadIdx.x & 31, ty = threadIdx.x >> 5;
  int k0 = by * 32, n0 = bx * 32;
  for (int r = 0; r < 32; r += 8)
    tile[ty + r][tx] = (bf16)W[(size_t)(k0 + ty + r) * H_ + n0 + tx];
  __syncthreads();
  for (int r = 0; r < 32; r += 8)
    wxp[(size_t)(gate * H_ + n0 + ty + r) * I_ + k0 + tx] = tile[tx][ty + r];
}

// Wh packed: whp[blk][k>>3][gate*16 + (u&15)][k&7] = W[k][u],  blk = u>>4
__global__ __launch_bounds__(256) void k_pack_wh(const float* __restrict__ W,
                                                 bf16* __restrict__ whp, int gate) {
  __shared__ bf16 tile[32][33];
  int bx = blockIdx.x & 31, by = blockIdx.x >> 5;
  int tx = threadIdx.x & 31, ty = threadIdx.x >> 5;
  int k0 = by * 32, u0 = bx * 32;
  for (int r = 0; r < 32; r += 8)
    tile[ty + r][tx] = (bf16)W[(size_t)(k0 + ty + r) * H_ + u0 + tx];
  __syncthreads();
  for (int r = 0; r < 32; r += 8) {
    int u = u0 + ty + r;
    int k = k0 + tx;
    size_t addr = ((size_t)(u >> 4) * 128 + (k >> 3)) * 512 +
                  (size_t)(gate * 16 + (u & 15)) * 8 + (k & 7);
    whp[addr] = tile[tx][ty + r];
  }
}

// ---------------- phase 1: xg = x @ Wx  (bf16 MFMA, m97-style) ----------------
__global__ __launch_bounds__(256) void k_gemm_xg(const bf16* __restrict__ A,
                                                 const bf16* __restrict__ Bt,
                                                 bf16* __restrict__ xg) {
  __shared__ bf16 As[128 * 64];
  __shared__ bf16 Bs[128 * 64];
  int bid = blockIdx.x;
  int bm = bid >> 5, bn = bid & 31;
  int m0 = bm * 128, n0 = bn * 128;
  int tid = threadIdx.x, lane = tid & 63, w = tid >> 6;
  int lr = lane & 15, lk = lane >> 4;
  int sr = lane >> 3, sk = (lane & 7) * 8;
  int wm = (w >> 1) * 64, wn = (w & 1) * 64;
  f32x4 acc[4][4] = {};

  for (int k0 = 0; k0 < 1024; k0 += 64) {
    __syncthreads();
    for (int i = 0; i < 4; ++i) {
      int idx = w * 4 + i;
      const bf16* ga = A + (size_t)(m0 + idx * 8 + sr) * 1024 + k0 + sk;
      GLD_LDS16(ga, &As[idx * 512]);
      const bf16* gb = Bt + (size_t)(n0 + idx * 8 + sr) * 1024 + k0 + sk;
      GLD_LDS16(gb, &Bs[idx * 512]);
    }
    asm volatile("s_waitcnt vmcnt(0)" ::: "memory");
    __syncthreads();
#pragma unroll
    for (int kk = 0; kk < 64; kk += 32) {
      bf16x8 af[4], bfr[4];
#pragma unroll
      for (int i = 0; i < 4; ++i)
        af[i] = *(const bf16x8*)&As[(wm + i * 16 + lr) * 64 + kk + lk * 8];
#pragma unroll
      for (int j = 0; j < 4; ++j)
        bfr[j] = *(const bf16x8*)&Bs[(wn + j * 16 + lr) * 64 + kk + lk * 8];
#pragma unroll
      for (int i = 0; i < 4; ++i)
#pragma unroll
        for (int j = 0; j < 4; ++j)
          acc[i][j] = __builtin_amdgcn_mfma_f32_16x16x32_bf16(af[i], bfr[j], acc[i][j], 0, 0, 0);
    }
  }
  // epilogue: scatter into xg[t][blk][b][c],  blk = u>>4, c = gate*16 + (u&15)
#pragma unroll
  for (int i = 0; i < 4; ++i) {
#pragma unroll
    for (int j = 0; j < 4; ++j) {
      int n = n0 + wn + j * 16 + lr;
      int u = n & 1023, g = n >> 10;
      int blk = u >> 4, c = g * 16 + (u & 15);
      int mb = m0 + wm + i * 16 + lk * 4;
#pragma unroll
      for (int r = 0; r < 4; ++r) {
        int m = mb + r;
        int t = m & 511, bb = m >> 9;
        xg[(((size_t)t * NBL + blk) * B_ + bb) * 64 + c] = (bf16)acc[i][j][r];
      }
    }
  }
}

// ---------------- phase 2: persistent cooperative LSTM scan ----------------
// 64 blocks x 512 threads. Block owns 16 units (64 gate cols). Wh in LDS (128KB).
// h + flags via relaxed AGENT atomics (cache-bypassing; no fences — proven R3).
// R5 change: per-wave K-half sub-barrier — wave (kh) polls only the 32 producer
// flags of its K-half and starts loads+MFMAs immediately (no block-wide sync at
// step top). Decorrelates IF$ bursts, removes one sync from the serial path.
__global__ __launch_bounds__(512) void k_lstm(const bf16* __restrict__ xg,
                                              const bf16* __restrict__ whp,
                                              bf16* hb,              // [2][64][1024]
                                              float* __restrict__ out,
                                              unsigned* arr,         // [64] @ 32-u32 stride
                                              const float* __restrict__ bii, const float* __restrict__ bhi,
                                              const float* __restrict__ bif, const float* __restrict__ bhf,
                                              const float* __restrict__ big, const float* __restrict__ bhg,
                                              const float* __restrict__ bio, const float* __restrict__ bho) {
  __shared__ bf16 whl[65536];          // 128 KB: [kg][c][8]
  __shared__ float gl[64 * 65];        // padded rows: bank-spread
  int blk = blockIdx.x;
  int tid = threadIdx.x;
  int lane = tid & 63, w = tid >> 6;
  int lr = lane & 15, lk = lane >> 4;
  int wm = (w >> 1) * 16;   // row-group (batch rows)
  int kh = w & 1;           // K half

  {  // stage Wh slice: 128KB contiguous
    const bf16* src = whp + (size_t)blk * 65536;
#pragma unroll
    for (int i = 0; i < 16; ++i)
      *(bf16x8*)&whl[(size_t)(i * 512 + tid) * 8] = *(const bf16x8*)&src[(size_t)(i * 512 + tid) * 8];
  }

  // elementwise mapping: thread -> (batch b, unit pair 2*eu2, 2*eu2+1)
  int eu2 = tid & 7, b = tid >> 3;
  int u0g = blk * NJ + eu2 * 2, u1g = u0g + 1;
  float bi0 = bii[u0g] + bhi[u0g], bi1 = bii[u1g] + bhi[u1g];
  float bf0 = bif[u0g] + bhf[u0g], bf1 = bif[u1g] + bhf[u1g];
  float bg0 = big[u0g] + bhg[u0g], bg1 = big[u1g] + bhg[u1g];
  float bo0 = bio[u0g] + bho[u0g], bo1 = bio[u1g] + bho[u1g];
  float c0 = 0.f, c1 = 0.f;

  // xg preload t=0: 4 u32 words (2 bf16 each), one per gate
  const unsigned* xgw = (const unsigned*)xg;
  unsigned xv[4];
  {
    size_t xb = (((size_t)0 * NBL + blk) * B_ + b) * 32 + eu2;
#pragma unroll
    for (int g = 0; g < 4; ++g) xv[g] = xgw[xb + g * 8];
  }
  __syncthreads();

  for (int t = 0; t < T_; ++t) {
    // ---- per-wave K-half sub-barrier: my 32 producers' flags >= t ----
    if (t > 0) {
      unsigned v;
      do {
        v = __hip_atomic_load(arr + (kh * 32 + (lane & 31)) * 32,
                              __ATOMIC_RELAXED, __HIP_MEMORY_SCOPE_AGENT);
      } while (!__all((int)(v >= (unsigned)t)));
      __builtin_amdgcn_sched_barrier(0);
    }

    // ---- preload A-fragments (h rows, my K-half) via relaxed agent atomics ----
    union { u64 q[2]; bf16x8 v; } af[16];
    const u64* hq = (const u64*)hb + (size_t)(t & 1) * 16384 + (wm + lr) * 256 + kh * 128 + lk * 2;
#pragma unroll
    for (int i = 0; i < 16; ++i) {
      af[i].q[0] = __hip_atomic_load(hq + i * 8,     __ATOMIC_RELAXED, __HIP_MEMORY_SCOPE_AGENT);
      af[i].q[1] = __hip_atomic_load(hq + i * 8 + 1, __ATOMIC_RELAXED, __HIP_MEMORY_SCOPE_AGENT);
    }

    // ---- GEMM: gl[64][64] += h @ WhSlice (wave: 16 rows x K-half x 64 cols) ----
    f32x4 acc[4] = {};
#pragma unroll
    for (int i = 0; i < 16; ++i) {
      int kg = kh * 64 + i * 4 + lk;
#pragma unroll
      for (int nt = 0; nt < 4; ++nt) {
        bf16x8 bb = *(const bf16x8*)&whl[(kg * 64 + nt * 16 + lr) * 8];
        acc[nt] = __builtin_amdgcn_mfma_f32_16x16x32_bf16(af[i].v, bb, acc[nt], 0, 0, 0);
      }
    }
    int grow = wm + lk * 4;
    if (kh == 0) {
#pragma unroll
      for (int nt = 0; nt < 4; ++nt)
#pragma unroll
        for (int r = 0; r < 4; ++r)
          gl[(grow + r) * 65 + nt * 16 + lr] = acc[nt][r];
    }
    __syncthreads();   // kh0 partials visible
    if (kh == 1) {
#pragma unroll
      for (int nt = 0; nt < 4; ++nt)
#pragma unroll
        for (int r = 0; r < 4; ++r)
          gl[(grow + r) * 65 + nt * 16 + lr] += acc[nt][r];
    }
    __syncthreads();   // full gate pre-activations ready

    // ---- gates + state update (1 batch x 2 units per thread) ----
    int gb = b * 65 + eu2 * 2;
    float gi0 = gl[gb]          + lo2f(xv[0]) + bi0;
    float gi1 = gl[gb + 1]      + hi2f(xv[0]) + bi1;
    float gf0 = gl[gb + 16]     + lo2f(xv[1]) + bf0;
    float gf1 = gl[gb + 17]     + hi2f(xv[1]) + bf1;
    float gg0 = gl[gb + 32]     + lo2f(xv[2]) + bg0;
    float gg1 = gl[gb + 33]     + hi2f(xv[2]) + bg1;
    float go0 = gl[gb + 48]     + lo2f(xv[3]) + bo0;
    float go1 = gl[gb + 49]     + hi2f(xv[3]) + bo1;
    c0 = sigmoidf_(gf0) * c0 + sigmoidf_(gi0) * tanhf_(gg0);
    c1 = sigmoidf_(gf1) * c1 + sigmoidf_(gi1) * tanhf_(gg1);
    float hv0 = sigmoidf_(go0) * tanhf_(c0);
    float hv1 = sigmoidf_(go1) * tanhf_(c1);

    if (t == T_ - 1) {
      out[(size_t)b * H_ + u0g] = hv0;
      out[(size_t)b * H_ + u1g] = hv1;
      out[(size_t)B_ * H_ + b * H_ + u0g] = c0;
      out[(size_t)B_ * H_ + b * H_ + u1g] = c1;
      break;  // no barrier after last step
    }

    // ---- publish h(t+1): packed 2xbf16 per thread, relaxed agent store ----
    unsigned hp = (unsigned)b2s((bf16)hv0) | ((unsigned)b2s((bf16)hv1) << 16);
    unsigned* hw = (unsigned*)(hb + (size_t)((t + 1) & 1) * (B_ * H_));
    __hip_atomic_store(hw + b * 512 + blk * 8 + eu2, hp, __ATOMIC_RELAXED, __HIP_MEMORY_SCOPE_AGENT);

    // drain this wave's stores, then block-wide sync, then arm flag
    asm volatile("s_waitcnt vmcnt(0)" ::: "memory");
    __syncthreads();
    if (tid == 0)
      __hip_atomic_store(arr + blk * 32, (unsigned)(t + 1), __ATOMIC_RELAXED, __HIP_MEMORY_SCOPE_AGENT);

    // xg prefetch for t+1 (latency hides under next poll)
    {
      size_t xb = (((size_t)(t + 1) * NBL + blk) * B_ + b) * 32 + eu2;
#pragma unroll
      for (int g = 0; g < 4; ++g) xv[g] = xgw[xb + g * 8];
    }
  }
}

// ---------------- launcher ----------------

extern "C" void kernel_launch(void* const* d_in, const int* in_sizes, int n_in,
                              void* d_out, int out_size, void* d_ws, size_t ws_size,
                              hipStream_t stream) {
  if (ws_size < WS_NEED) return;

  const float* x = (const float*)d_in[0];
  const float* W_ii = (const float*)d_in[1];
  const float* W_hi = (const float*)d_in[2];
  const float* W_if = (const float*)d_in[3];
  const float* W_hf = (const float*)d_in[4];
  const float* W_ig = (const float*)d_in[5];
  const float* W_hg = (const float*)d_in[6];
  const float* W_io = (const float*)d_in[7];
  const float* W_ho = (const float*)d_in[8];
  const float* b_ii = (const float*)d_in[9];
  const float* b_hi = (const float*)d_in[10];
  const float* b_if = (const float*)d_in[11];
  const float* b_hf = (const float*)d_in[12];
  const float* b_ig = (const float*)d_in[13];
  const float* b_hg = (const float*)d_in[14];
  const float* b_io = (const float*)d_in[15];
  const float* b_ho = (const float*)d_in[16];

  char* ws = (char*)d_ws;
  bf16* xbf = (bf16*)(ws + WS_XBF);
  bf16* wxp = (bf16*)(ws + WS_WXP);
  bf16* whp = (bf16*)(ws + WS_WHP);
  bf16* xgp = (bf16*)(ws + WS_XG);
  bf16* hbp = (bf16*)(ws + WS_HB);
  unsigned* arrp = (unsigned*)(ws + WS_ARR);
  float* outp = (float*)d_out;

  // zero h0 buffers + arrival flags (contiguous region)
  hipMemsetAsync(ws + WS_HB, 0, 262144 + 8192, stream);

  // pack
  k_cvt_x<<<2048, 256, 0, stream>>>((const float4*)x, xbf, BT_ * I_ / 4);
  const float* wx_g[4] = {W_ii, W_if, W_ig, W_io};
  const float* wh_g[4] = {W_hi, W_hf, W_hg, W_ho};
  for (int g = 0; g < 4; ++g) {
    k_pack_wx<<<1024, 256, 0, stream>>>(wx_g[g], wxp, g);
    k_pack_wh<<<1024, 256, 0, stream>>>(wh_g[g], whp, g);
  }

  // phase 1 GEMM
  k_gemm_xg<<<dim3(256 * 32), 256, 0, stream>>>(xbf, wxp, xgp);

  // phase 2 cooperative scan
  void* args[] = {
      (void*)&xgp, (void*)&whp, (void*)&hbp, (void*)&outp, (void*)&arrp,
      (void*)&b_ii, (void*)&b_hi, (void*)&b_if, (void*)&b_hf,
      (void*)&b_ig, (void*)&b_hg, (void*)&b_io, (void*)&b_ho};
  hipLaunchCooperativeKernel((const void*)k_lstm, dim3(NBL), dim3(512), args, 0, stream);
}

// Round 7
// 4006.524 us; speedup vs baseline: 3.2798x; 1.3777x over previous
//
#include <hip/hip_runtime.h>
#include <cstdint>
#include <cstddef>
#include <string.h>

typedef __bf16 bf16;
typedef bf16 bf16x4 __attribute__((ext_vector_type(4)));
typedef bf16 bf16x8 __attribute__((ext_vector_type(8)));
typedef float f32x4 __attribute__((ext_vector_type(4)));
typedef unsigned long long u64;

#define B_   64
#define T_   512
#define I_   1024
#define H_   1024
#define BT_  32768
#define NBL  64    // lstm blocks
#define NJ   16    // hidden units per lstm block

// ---- ws layout (bytes) ----
#define WS_XBF   ((size_t)0)              // x as bf16 [32768][1024]            : 67108864
#define WS_WXP   ((size_t)67108864)       // Wx^T bf16 [4096][1024]             : 8388608
#define WS_WHP   ((size_t)75497472)       // Wh packed bf16 [64][128][64][8]    : 8388608
#define WS_XG    ((size_t)83886080)       // xg bf16 [512][64][64][64]          : 268435456
#define WS_HB    ((size_t)352321536)      // h dbuf bf16 [2][64][1024]          : 262144
#define WS_ARR   ((size_t)352583680)      // flags u32[64] @128B stride         : 8192
#define WS_NEED  ((size_t)352600064)

#define GLD_LDS16(gptr, lptr) \
  __builtin_amdgcn_global_load_lds((const __attribute__((address_space(1))) void*)(gptr), \
                                   (__attribute__((address_space(3))) void*)(lptr), 16, 0, 0)

__device__ __forceinline__ float sigmoidf_(float x) { return 1.0f / (1.0f + __expf(-x)); }
// branch-free tanh: 1 - 2/(e^{2x}+1); saturates correctly for |x| large (no NaN).
__device__ __forceinline__ float tanhf_(float x) { float e = __expf(2.0f * x); return 1.0f - 2.0f / (e + 1.0f); }
__device__ __forceinline__ float lo2f(unsigned u) { unsigned v = u << 16; float f; memcpy(&f, &v, 4); return f; }
__device__ __forceinline__ float hi2f(unsigned u) { unsigned v = u & 0xffff0000u; float f; memcpy(&f, &v, 4); return f; }
__device__ __forceinline__ unsigned short b2s(bf16 h) { unsigned short s; memcpy(&s, &h, 2); return s; }

// ---------------- pack kernels ----------------

__global__ __launch_bounds__(256) void k_cvt_x(const float4* __restrict__ in,
                                               bf16* __restrict__ out, int n4) {
  int i = blockIdx.x * blockDim.x + threadIdx.x;
  int stride = gridDim.x * blockDim.x;
  for (; i < n4; i += stride) {
    float4 v = in[i];
    bf16x4 r = { (bf16)v.x, (bf16)v.y, (bf16)v.z, (bf16)v.w };
    *(bf16x4*)(out + (size_t)i * 4) = r;
  }
}

// Wx^T: wxp[(gate*1024 + n)][k] = W[k][n]   (32x32 LDS tile transpose)
__global__ __launch_bounds__(256) void k_pack_wx(const float* __restrict__ W,
                                                 bf16* __restrict__ wxp, int gate) {
  __shared__ bf16 tile[32][33];
  int bx = blockIdx.x & 31, by = blockIdx.x >> 5;
  int tx = threadIdx.x & 31, ty = threadIdx.x >> 5;
  int k0 = by * 32, n0 = bx * 32;
  for (int r = 0; r < 32; r += 8)
    tile[ty + r][tx] = (bf16)W[(size_t)(k0 + ty + r) * H_ + n0 + tx];
  __syncthreads();
  for (int r = 0; r < 32; r += 8)
    wxp[(size_t)(gate * H_ + n0 + ty + r) * I_ + k0 + tx] = tile[tx][ty + r];
}

// Wh packed: whp[blk][k>>3][gate*16 + (u&15)][k&7] = W[k][u],  blk = u>>4
__global__ __launch_bounds__(256) void k_pack_wh(const float* __restrict__ W,
                                                 bf16* __restrict__ whp, int gate) {
  __shared__ bf16 tile[32][33];
  int bx = blockIdx.x & 31, by = blockIdx.x >> 5;
  int tx = threadIdx.x & 31, ty = threadIdx.x >> 5;
  int k0 = by * 32, u0 = bx * 32;
  for (int r = 0; r < 32; r += 8)
    tile[ty + r][tx] = (bf16)W[(size_t)(k0 + ty + r) * H_ + u0 + tx];
  __syncthreads();
  for (int r = 0; r < 32; r += 8) {
    int u = u0 + ty + r;
    int k = k0 + tx;
    size_t addr = ((size_t)(u >> 4) * 128 + (k >> 3)) * 512 +
                  (size_t)(gate * 16 + (u & 15)) * 8 + (k & 7);
    whp[addr] = tile[tx][ty + r];
  }
}

// ---------------- phase 1: xg = x @ Wx  (bf16 MFMA, m97-style) ----------------
__global__ __launch_bounds__(256) void k_gemm_xg(const bf16* __restrict__ A,
                                                 const bf16* __restrict__ Bt,
                                                 bf16* __restrict__ xg) {
  __shared__ bf16 As[128 * 64];
  __shared__ bf16 Bs[128 * 64];
  int bid = blockIdx.x;
  int bm = bid >> 5, bn = bid & 31;
  int m0 = bm * 128, n0 = bn * 128;
  int tid = threadIdx.x, lane = tid & 63, w = tid >> 6;
  int lr = lane & 15, lk = lane >> 4;
  int sr = lane >> 3, sk = (lane & 7) * 8;
  int wm = (w >> 1) * 64, wn = (w & 1) * 64;
  f32x4 acc[4][4] = {};

  for (int k0 = 0; k0 < 1024; k0 += 64) {
    __syncthreads();
    for (int i = 0; i < 4; ++i) {
      int idx = w * 4 + i;
      const bf16* ga = A + (size_t)(m0 + idx * 8 + sr) * 1024 + k0 + sk;
      GLD_LDS16(ga, &As[idx * 512]);
      const bf16* gb = Bt + (size_t)(n0 + idx * 8 + sr) * 1024 + k0 + sk;
      GLD_LDS16(gb, &Bs[idx * 512]);
    }
    asm volatile("s_waitcnt vmcnt(0)" ::: "memory");
    __syncthreads();
#pragma unroll
    for (int kk = 0; kk < 64; kk += 32) {
      bf16x8 af[4], bfr[4];
#pragma unroll
      for (int i = 0; i < 4; ++i)
        af[i] = *(const bf16x8*)&As[(wm + i * 16 + lr) * 64 + kk + lk * 8];
#pragma unroll
      for (int j = 0; j < 4; ++j)
        bfr[j] = *(const bf16x8*)&Bs[(wn + j * 16 + lr) * 64 + kk + lk * 8];
#pragma unroll
      for (int i = 0; i < 4; ++i)
#pragma unroll
        for (int j = 0; j < 4; ++j)
          acc[i][j] = __builtin_amdgcn_mfma_f32_16x16x32_bf16(af[i], bfr[j], acc[i][j], 0, 0, 0);
    }
  }
  // epilogue: scatter into xg[t][blk][b][c],  blk = u>>4, c = gate*16 + (u&15)
#pragma unroll
  for (int i = 0; i < 4; ++i) {
#pragma unroll
    for (int j = 0; j < 4; ++j) {
      int n = n0 + wn + j * 16 + lr;
      int u = n & 1023, g = n >> 10;
      int blk = u >> 4, c = g * 16 + (u & 15);
      int mb = m0 + wm + i * 16 + lk * 4;
#pragma unroll
      for (int r = 0; r < 4; ++r) {
        int m = mb + r;
        int t = m & 511, bb = m >> 9;
        xg[(((size_t)t * NBL + blk) * B_ + bb) * 64 + c] = (bf16)acc[i][j][r];
      }
    }
  }
}

// ---------------- phase 2: persistent cooperative LSTM scan ----------------
// 64 blocks x 512 threads. Block owns 16 units (64 gate cols). Wh in LDS (128KB).
// h + flags via coherence-point accesses (sc0 sc1 = bypass L1+L2; same semantics
// as the proven R3/R5 relaxed agent atomics, but vectorized 16B and pipelined).
// R7: counted-vmcnt pipeline — issue 16 h-loads + 4 xg loads, consume in 4 MFMA
// groups gated by s_waitcnt vmcnt(16/12/8/4); h-load latency hides under MFMA.
__global__ __launch_bounds__(512) void k_lstm(const bf16* __restrict__ xg,
                                              const bf16* __restrict__ whp,
                                              bf16* hb,              // [2][64][1024]
                                              float* __restrict__ out,
                                              unsigned* arr,         // [64] @ 32-u32 stride
                                              const float* __restrict__ bii, const float* __restrict__ bhi,
                                              const float* __restrict__ bif, const float* __restrict__ bhf,
                                              const float* __restrict__ big, const float* __restrict__ bhg,
                                              const float* __restrict__ bio, const float* __restrict__ bho) {
  __shared__ bf16 whl[65536];          // 128 KB: [kg][c][8]
  __shared__ float gl[64 * 65];        // padded rows: bank-spread
  int blk = blockIdx.x;
  int tid = threadIdx.x;
  int lane = tid & 63, w = tid >> 6;
  int lr = lane & 15, lk = lane >> 4;
  int wm = (w >> 1) * 16;   // row-group (batch rows)
  int kh = w & 1;           // K half

  {  // stage Wh slice: 128KB contiguous
    const bf16* src = whp + (size_t)blk * 65536;
#pragma unroll
    for (int i = 0; i < 16; ++i)
      *(bf16x8*)&whl[(size_t)(i * 512 + tid) * 8] = *(const bf16x8*)&src[(size_t)(i * 512 + tid) * 8];
  }

  // elementwise mapping: thread -> (batch b, unit pair 2*eu2, 2*eu2+1)
  int eu2 = tid & 7, b = tid >> 3;
  int u0g = blk * NJ + eu2 * 2, u1g = u0g + 1;
  float bi0 = bii[u0g] + bhi[u0g], bi1 = bii[u1g] + bhi[u1g];
  float bf0 = bif[u0g] + bhf[u0g], bf1 = bif[u1g] + bhf[u1g];
  float bg0 = big[u0g] + bhg[u0g], bg1 = big[u1g] + bhg[u1g];
  float bo0 = bio[u0g] + bho[u0g], bo1 = bio[u1g] + bho[u1g];
  float c0 = 0.f, c1 = 0.f;

  const char* hb_c = (const char*)hb;
  __syncthreads();

  for (int t = 0; t < T_; ++t) {
    // ---- per-wave K-half sub-barrier: my 32 producers' flags >= t ----
    if (t > 0) {
      unsigned v;
      do {
        v = __hip_atomic_load(arr + (kh * 32 + (lane & 31)) * 32,
                              __ATOMIC_RELAXED, __HIP_MEMORY_SCOPE_AGENT);
      } while (!__all((int)(v >= (unsigned)t)));
      __builtin_amdgcn_sched_barrier(0);
    }

    // ---- issue h-loads: 16 x 16B, sc0 sc1 (coherence-point reads, pipelined) ----
    bf16x8 af[16];
    const char* hbase = hb_c + (size_t)(t & 1) * 131072 + (size_t)(wm + lr) * 2048 +
                        (size_t)kh * 1024 + (size_t)lk * 16;
#pragma unroll
    for (int i = 0; i < 16; ++i)
      asm volatile("global_load_dwordx4 %0, %1, off sc0 sc1"
                   : "=v"(af[i]) : "v"(hbase + (size_t)i * 64));

    // ---- issue xg loads for this step (4 x 4B, cached; hidden under MFMAs) ----
    unsigned xv[4];
    const char* xgb = (const char*)xg + (((size_t)t * NBL + blk) * B_ + b) * 128 + eu2 * 4;
#pragma unroll
    for (int g = 0; g < 4; ++g)
      asm volatile("global_load_dword %0, %1, off"
                   : "=v"(xv[g]) : "v"(xgb + (size_t)g * 32));

    // ---- GEMM: 4 groups of 4 af's, gated by counted vmcnt (20 outstanding) ----
    f32x4 acc[4] = {};
#define MFMA_GRP(G)                                                                   \
    _Pragma("unroll")                                                                 \
    for (int ii = 0; ii < 4; ++ii) {                                                  \
      int i = (G) * 4 + ii;                                                           \
      int kg = kh * 64 + i * 4 + lk;                                                  \
      _Pragma("unroll")                                                               \
      for (int nt = 0; nt < 4; ++nt) {                                                \
        bf16x8 bb = *(const bf16x8*)&whl[(kg * 64 + nt * 16 + lr) * 8];               \
        acc[nt] = __builtin_amdgcn_mfma_f32_16x16x32_bf16(af[i], bb, acc[nt], 0, 0, 0); \
      }                                                                               \
    }
    asm volatile("s_waitcnt vmcnt(16)" ::: "memory");
    __builtin_amdgcn_sched_barrier(0);
    MFMA_GRP(0)
    asm volatile("s_waitcnt vmcnt(12)" ::: "memory");
    __builtin_amdgcn_sched_barrier(0);
    MFMA_GRP(1)
    asm volatile("s_waitcnt vmcnt(8)" ::: "memory");
    __builtin_amdgcn_sched_barrier(0);
    MFMA_GRP(2)
    asm volatile("s_waitcnt vmcnt(4)" ::: "memory");
    __builtin_amdgcn_sched_barrier(0);
    MFMA_GRP(3)
#undef MFMA_GRP

    int grow = wm + lk * 4;
    if (kh == 0) {
#pragma unroll
      for (int nt = 0; nt < 4; ++nt)
#pragma unroll
        for (int r = 0; r < 4; ++r)
          gl[(grow + r) * 65 + nt * 16 + lr] = acc[nt][r];
    }
    __syncthreads();   // kh0 partials visible
    if (kh == 1) {
#pragma unroll
      for (int nt = 0; nt < 4; ++nt)
#pragma unroll
        for (int r = 0; r < 4; ++r)
          gl[(grow + r) * 65 + nt * 16 + lr] += acc[nt][r];
    }
    __syncthreads();   // full gate pre-activations ready

    // ---- gates + state update (xv must be landed) ----
    asm volatile("s_waitcnt vmcnt(0)" ::: "memory");
    __builtin_amdgcn_sched_barrier(0);
    int gb = b * 65 + eu2 * 2;
    float gi0 = gl[gb]          + lo2f(xv[0]) + bi0;
    float gi1 = gl[gb + 1]      + hi2f(xv[0]) + bi1;
    float gf0 = gl[gb + 16]     + lo2f(xv[1]) + bf0;
    float gf1 = gl[gb + 17]     + hi2f(xv[1]) + bf1;
    float gg0 = gl[gb + 32]     + lo2f(xv[2]) + bg0;
    float gg1 = gl[gb + 33]     + hi2f(xv[2]) + bg1;
    float go0 = gl[gb + 48]     + lo2f(xv[3]) + bo0;
    float go1 = gl[gb + 49]     + hi2f(xv[3]) + bo1;
    c0 = sigmoidf_(gf0) * c0 + sigmoidf_(gi0) * tanhf_(gg0);
    c1 = sigmoidf_(gf1) * c1 + sigmoidf_(gi1) * tanhf_(gg1);
    float hv0 = sigmoidf_(go0) * tanhf_(c0);
    float hv1 = sigmoidf_(go1) * tanhf_(c1);

    if (t == T_ - 1) {
      out[(size_t)b * H_ + u0g] = hv0;
      out[(size_t)b * H_ + u1g] = hv1;
      out[(size_t)B_ * H_ + b * H_ + u0g] = c0;
      out[(size_t)B_ * H_ + b * H_ + u1g] = c1;
      break;  // no barrier after last step
    }

    // ---- publish h(t+1): packed 2xbf16 per thread, relaxed agent store ----
    unsigned hp = (unsigned)b2s((bf16)hv0) | ((unsigned)b2s((bf16)hv1) << 16);
    unsigned* hw = (unsigned*)(hb + (size_t)((t + 1) & 1) * (B_ * H_));
    __hip_atomic_store(hw + b * 512 + blk * 8 + eu2, hp, __ATOMIC_RELAXED, __HIP_MEMORY_SCOPE_AGENT);

    // drain this wave's stores, then block-wide sync, then arm flag
    asm volatile("s_waitcnt vmcnt(0)" ::: "memory");
    __syncthreads();
    if (tid == 0)
      __hip_atomic_store(arr + blk * 32, (unsigned)(t + 1), __ATOMIC_RELAXED, __HIP_MEMORY_SCOPE_AGENT);
  }
}

// ---------------- launcher ----------------

extern "C" void kernel_launch(void* const* d_in, const int* in_sizes, int n_in,
                              void* d_out, int out_size, void* d_ws, size_t ws_size,
                              hipStream_t stream) {
  if (ws_size < WS_NEED) return;

  const float* x = (const float*)d_in[0];
  const float* W_ii = (const float*)d_in[1];
  const float* W_hi = (const float*)d_in[2];
  const float* W_if = (const float*)d_in[3];
  const float* W_hf = (const float*)d_in[4];
  const float* W_ig = (const float*)d_in[5];
  const float* W_hg = (const float*)d_in[6];
  const float* W_io = (const float*)d_in[7];
  const float* W_ho = (const float*)d_in[8];
  const float* b_ii = (const float*)d_in[9];
  const float* b_hi = (const float*)d_in[10];
  const float* b_if = (const float*)d_in[11];
  const float* b_hf = (const float*)d_in[12];
  const float* b_ig = (const float*)d_in[13];
  const float* b_hg = (const float*)d_in[14];
  const float* b_io = (const float*)d_in[15];
  const float* b_ho = (const float*)d_in[16];

  char* ws = (char*)d_ws;
  bf16* xbf = (bf16*)(ws + WS_XBF);
  bf16* wxp = (bf16*)(ws + WS_WXP);
  bf16* whp = (bf16*)(ws + WS_WHP);
  bf16* xgp = (bf16*)(ws + WS_XG);
  bf16* hbp = (bf16*)(ws + WS_HB);
  unsigned* arrp = (unsigned*)(ws + WS_ARR);
  float* outp = (float*)d_out;

  // zero h0 buffers + arrival flags (contiguous region)
  hipMemsetAsync(ws + WS_HB, 0, 262144 + 8192, stream);

  // pack
  k_cvt_x<<<2048, 256, 0, stream>>>((const float4*)x, xbf, BT_ * I_ / 4);
  const float* wx_g[4] = {W_ii, W_if, W_ig, W_io};
  const float* wh_g[4] = {W_hi, W_hf, W_hg, W_ho};
  for (int g = 0; g < 4; ++g) {
    k_pack_wx<<<1024, 256, 0, stream>>>(wx_g[g], wxp, g);
    k_pack_wh<<<1024, 256, 0, stream>>>(wh_g[g], whp, g);
  }

  // phase 1 GEMM
  k_gemm_xg<<<dim3(256 * 32), 256, 0, stream>>>(xbf, wxp, xgp);

  // phase 2 cooperative scan
  void* args[] = {
      (void*)&xgp, (void*)&whp, (void*)&hbp, (void*)&outp, (void*)&arrp,
      (void*)&b_ii, (void*)&b_hi, (void*)&b_if, (void*)&b_hf,
      (void*)&b_ig, (void*)&b_hg, (void*)&b_io, (void*)&b_ho};
  hipLaunchCooperativeKernel((const void*)k_lstm, dim3(NBL), dim3(512), args, 0, stream);
}